// Round 1
// baseline (316.975 us; speedup 1.0000x reference)
//
#include <hip/hip_runtime.h>

typedef __attribute__((ext_vector_type(8))) short bf16x8;
typedef __attribute__((ext_vector_type(4))) float f32x4;
typedef __attribute__((ext_vector_type(4))) unsigned short u16x4;

#define DEVI static __device__ __forceinline__

DEVI float bf2f(unsigned short u) {
    union { unsigned int ui; float f; } c; c.ui = ((unsigned int)u) << 16; return c.f;
}
DEVI unsigned short f2bf(float f) {
    union { float f; unsigned int ui; } c; c.f = f;
    unsigned int u = c.ui;
    u += 0x7FFFu + ((u >> 16) & 1u);
    return (unsigned short)(u >> 16);
}

#define NRES 320
#define NN   102400
#define CCH  128
#define NPAD 344   // 320 + 24: keeps 16B row alignment, stride 172 dwords == 12 mod 32 (~2-way banks)

// ---------------- Kernel 1: LayerNorm -> xn(bf16) + bterm ----------------
__global__ __launch_bounds__(256) void k_ln_bias(
    const float* __restrict__ x2d, const float* __restrict__ ln_g,
    const float* __restrict__ ln_b, const float* __restrict__ wb,
    unsigned short* __restrict__ xn, float* __restrict__ bterm)
{
    int wave = threadIdx.x >> 6, lane = threadIdx.x & 63;
    int r = blockIdx.x * 4 + wave;
    int c0 = lane * 2;
    float2 x = *(const float2*)(x2d + (size_t)r * CCH + c0);
    float s = x.x + x.y, sq = x.x * x.x + x.y * x.y;
    #pragma unroll
    for (int m = 1; m < 64; m <<= 1) { s += __shfl_xor(s, m, 64); sq += __shfl_xor(sq, m, 64); }
    float mu = s * (1.0f / 128.0f);
    float var = sq * (1.0f / 128.0f) - mu * mu;
    float rstd = rsqrtf(var + 1e-5f);
    float xn0 = (x.x - mu) * rstd * ln_g[c0] + ln_b[c0];
    float xn1 = (x.y - mu) * rstd * ln_g[c0 + 1] + ln_b[c0 + 1];
    unsigned int packed = (unsigned int)f2bf(xn0) | ((unsigned int)f2bf(xn1) << 16);
    *(unsigned int*)(xn + (size_t)r * CCH + c0) = packed;
    // bterm[h,i,j] = sum_c xn[i,j,c] * wb[c,h]
    float4 w0 = *(const float4*)(wb + c0 * 4);
    float4 w1 = *(const float4*)(wb + c0 * 4 + 4);
    float b0 = xn0 * w0.x + xn1 * w1.x;
    float b1 = xn0 * w0.y + xn1 * w1.y;
    float b2 = xn0 * w0.z + xn1 * w1.z;
    float b3 = xn0 * w0.w + xn1 * w1.w;
    #pragma unroll
    for (int m = 1; m < 64; m <<= 1) {
        b0 += __shfl_xor(b0, m, 64); b1 += __shfl_xor(b1, m, 64);
        b2 += __shfl_xor(b2, m, 64); b3 += __shfl_xor(b3, m, 64);
    }
    if (lane == 0) {
        bterm[0 * NN + r] = b0; bterm[1 * NN + r] = b1;
        bterm[2 * NN + r] = b2; bterm[3 * NN + r] = b3;
    }
}

// ---------------- Kernel 2: qkvg = xn @ [wq|wk|wv|wg] (sigmoid on g) ----------------
__global__ __launch_bounds__(256) void k_proj(
    const unsigned short* __restrict__ xn,
    const float* __restrict__ wq, const float* __restrict__ wk,
    const float* __restrict__ wv, const float* __restrict__ wg,
    const float* __restrict__ bg,
    unsigned short* __restrict__ qkvg)
{
    __shared__ unsigned short A[128][136];
    __shared__ unsigned short Bt[128][136];   // Bt[n][k]
    int mt = blockIdx.x, nt = blockIdx.y;
    int m0 = mt * 128;
    const float* wsrc = (nt == 0) ? wq : (nt == 1) ? wk : (nt == 2) ? wv : wg;
    int t = threadIdx.x;
    #pragma unroll
    for (int it = 0; it < 8; ++it) {
        int idx = it * 256 + t;
        int row = idx >> 4, chunk = idx & 15;
        *(bf16x8*)(&A[row][chunk * 8]) = *(const bf16x8*)(xn + (size_t)(m0 + row) * CCH + chunk * 8);
    }
    #pragma unroll
    for (int it = 0; it < 16; ++it) {
        int k = it * 8 + (t >> 5);
        int n4 = (t & 31) * 4;
        float4 w = *(const float4*)(wsrc + k * 128 + n4);
        Bt[n4 + 0][k] = f2bf(w.x); Bt[n4 + 1][k] = f2bf(w.y);
        Bt[n4 + 2][k] = f2bf(w.z); Bt[n4 + 3][k] = f2bf(w.w);
    }
    __syncthreads();
    int wave = t >> 6, lane = t & 63;
    int wr = (wave >> 1) * 64, wc = (wave & 1) * 64;
    int li = lane & 15, lk = (lane >> 4) * 8;
    f32x4 acc[4][4] = {};
    #pragma unroll
    for (int kk = 0; kk < 4; ++kk) {
        bf16x8 af[4], bfr[4];
        #pragma unroll
        for (int i = 0; i < 4; ++i) af[i] = *(const bf16x8*)(&A[wr + i * 16 + li][kk * 32 + lk]);
        #pragma unroll
        for (int j = 0; j < 4; ++j) bfr[j] = *(const bf16x8*)(&Bt[wc + j * 16 + li][kk * 32 + lk]);
        #pragma unroll
        for (int i = 0; i < 4; ++i)
            #pragma unroll
            for (int j = 0; j < 4; ++j)
                acc[i][j] = __builtin_amdgcn_mfma_f32_16x16x32_bf16(af[i], bfr[j], acc[i][j], 0, 0, 0);
    }
    int rbase = (lane >> 4) * 4;
    bool isg = (nt == 3);
    #pragma unroll
    for (int i = 0; i < 4; ++i) {
        #pragma unroll
        for (int j = 0; j < 4; ++j) {
            int col = wc + j * 16 + li;
            int gcol = nt * 128 + col;
            #pragma unroll
            for (int r = 0; r < 4; ++r) {
                int grow = m0 + wr + i * 16 + rbase + r;
                float v = acc[i][j][r];
                if (isg) { v += bg[col]; v = 1.0f / (1.0f + __expf(-v)); }
                qkvg[(size_t)grow * 512 + gcol] = f2bf(v);
            }
        }
    }
}

// ---------------- Kernel 3: fused attention per (m,h) ----------------
__global__ __launch_bounds__(256) void k_attn(
    const unsigned short* __restrict__ qkvg,
    const float* __restrict__ bterm,
    const float* __restrict__ mask,
    unsigned short* __restrict__ opre)
{
    __shared__ unsigned short Kl[320][40];     // K rows [j][dc], pad to 40
    __shared__ unsigned short VT[32][NPAD];    // V transposed [dc][j]
    __shared__ unsigned short Pl[4][16][NPAD]; // per-wave P [i_local][j]
    __shared__ float mb[320];
    int bid = blockIdx.x;
    int m = bid >> 2, h = bid & 3;
    int t = threadIdx.x;
    size_t base = (size_t)m * NRES * 512;
    // stage K rows (coalesced 64B per row)
    for (int j = t; j < NRES; j += 256) {
        const bf16x8* src = (const bf16x8*)(qkvg + base + (size_t)j * 512 + 128 + h * 32);
        bf16x8* dst = (bf16x8*)(&Kl[j][0]);
        dst[0] = src[0]; dst[1] = src[1]; dst[2] = src[2]; dst[3] = src[3];
    }
    // stage V transposed: thread (dc = t&31, jg = t>>5) covers j in [jg*40, jg*40+40)
    {
        int dc = t & 31, jg = t >> 5;
        #pragma unroll 4
        for (int jj = 0; jj < 40; jj += 2) {
            int j = jg * 40 + jj;
            unsigned short v0 = qkvg[base + (size_t)j * 512 + 256 + h * 32 + dc];
            unsigned short v1 = qkvg[base + (size_t)(j + 1) * 512 + 256 + h * 32 + dc];
            *(unsigned int*)(&VT[dc][j]) = (unsigned int)v0 | ((unsigned int)v1 << 16);
        }
    }
    for (int j = t; j < NRES; j += 256) mb[j] = 100000.0f * (mask[(size_t)m * NRES + j] - 1.0f);
    __syncthreads();

    int wave = t >> 6, lane = t & 63;
    int li = lane & 15, lg = lane >> 4;
    const float scale = 0.17677669529663687f;  // 1/sqrt(32)
    for (int c = 0; c < 5; ++c) {
        int i0 = wave * 80 + c * 16;
        int i = i0 + li;
        size_t qrow = base + (size_t)i * 512;
        bf16x8 qf = *(const bf16x8*)(qkvg + qrow + h * 32 + lg * 8);
        f32x4 z = {0.f, 0.f, 0.f, 0.f};
        f32x4 st[20];
        #pragma unroll
        for (int jf = 0; jf < 20; ++jf) {
            bf16x8 kf = *(const bf16x8*)(&Kl[jf * 16 + li][lg * 8]);
            st[jf] = __builtin_amdgcn_mfma_f32_16x16x32_bf16(kf, qf, z, 0, 0, 0);
        }
        // scale + pair-bias + mask-bias, row max (row = i, spread over lg groups)
        const float* brow = bterm + (size_t)h * NN + (size_t)i * NRES;
        float mx = -3.0e38f;
        #pragma unroll
        for (int jf = 0; jf < 20; ++jf) {
            int j0 = jf * 16 + lg * 4;
            float4 bb = *(const float4*)(brow + j0);
            float4 mm = *(const float4*)(&mb[j0]);
            st[jf][0] = st[jf][0] * scale + bb.x + mm.x;
            st[jf][1] = st[jf][1] * scale + bb.y + mm.y;
            st[jf][2] = st[jf][2] * scale + bb.z + mm.z;
            st[jf][3] = st[jf][3] * scale + bb.w + mm.w;
            mx = fmaxf(mx, fmaxf(fmaxf(st[jf][0], st[jf][1]), fmaxf(st[jf][2], st[jf][3])));
        }
        mx = fmaxf(mx, __shfl_xor(mx, 16, 64));
        mx = fmaxf(mx, __shfl_xor(mx, 32, 64));
        float sum = 0.0f;
        #pragma unroll
        for (int jf = 0; jf < 20; ++jf) {
            float p0 = __expf(st[jf][0] - mx);
            float p1 = __expf(st[jf][1] - mx);
            float p2 = __expf(st[jf][2] - mx);
            float p3 = __expf(st[jf][3] - mx);
            sum += (p0 + p1) + (p2 + p3);
            unsigned int lo = (unsigned int)f2bf(p0) | ((unsigned int)f2bf(p1) << 16);
            unsigned int hi = (unsigned int)f2bf(p2) | ((unsigned int)f2bf(p3) << 16);
            unsigned int* dst = (unsigned int*)(&Pl[wave][li][jf * 16 + lg * 4]);
            dst[0] = lo; dst[1] = hi;
        }
        sum += __shfl_xor(sum, 16, 64);
        sum += __shfl_xor(sum, 32, 64);
        // PV: out^T[dc,i] = sum_j V^T[dc,j] * P[i,j]
        f32x4 o0 = {0.f, 0.f, 0.f, 0.f}, o1 = {0.f, 0.f, 0.f, 0.f};
        #pragma unroll
        for (int kk = 0; kk < 10; ++kk) {
            bf16x8 pf = *(const bf16x8*)(&Pl[wave][li][kk * 32 + lg * 8]);
            bf16x8 va = *(const bf16x8*)(&VT[li][kk * 32 + lg * 8]);
            bf16x8 vb = *(const bf16x8*)(&VT[16 + li][kk * 32 + lg * 8]);
            o0 = __builtin_amdgcn_mfma_f32_16x16x32_bf16(va, pf, o0, 0, 0, 0);
            o1 = __builtin_amdgcn_mfma_f32_16x16x32_bf16(vb, pf, o1, 0, 0, 0);
        }
        float inv = 1.0f / sum;
        size_t orow = ((size_t)m * NRES + i) * CCH + h * 32;
        #pragma unroll
        for (int df = 0; df < 2; ++df) {
            f32x4 o = df ? o1 : o0;
            int dcb = df * 16 + lg * 4;
            u16x4 gv = *(const u16x4*)(qkvg + qrow + 384 + h * 32 + dcb);
            u16x4 ov;
            #pragma unroll
            for (int r = 0; r < 4; ++r) ov[r] = f2bf(o[r] * inv * bf2f(gv[r]));
            *(u16x4*)(opre + orow + dcb) = ov;
        }
    }
}

// ---------------- Kernel 4: out = opre @ wo + bo (f32 out) ----------------
__global__ __launch_bounds__(256) void k_out(
    const unsigned short* __restrict__ opre, const float* __restrict__ wo,
    const float* __restrict__ bo, float* __restrict__ out)
{
    __shared__ unsigned short A[128][136];
    __shared__ unsigned short Bt[128][136];
    int m0 = blockIdx.x * 128;
    int t = threadIdx.x;
    #pragma unroll
    for (int it = 0; it < 8; ++it) {
        int idx = it * 256 + t;
        int row = idx >> 4, chunk = idx & 15;
        *(bf16x8*)(&A[row][chunk * 8]) = *(const bf16x8*)(opre + (size_t)(m0 + row) * CCH + chunk * 8);
    }
    #pragma unroll
    for (int it = 0; it < 16; ++it) {
        int k = it * 8 + (t >> 5);
        int n4 = (t & 31) * 4;
        float4 w = *(const float4*)(wo + k * 128 + n4);
        Bt[n4 + 0][k] = f2bf(w.x); Bt[n4 + 1][k] = f2bf(w.y);
        Bt[n4 + 2][k] = f2bf(w.z); Bt[n4 + 3][k] = f2bf(w.w);
    }
    __syncthreads();
    int wave = t >> 6, lane = t & 63;
    int wr = (wave >> 1) * 64, wc = (wave & 1) * 64;
    int li = lane & 15, lk = (lane >> 4) * 8;
    f32x4 acc[4][4] = {};
    #pragma unroll
    for (int kk = 0; kk < 4; ++kk) {
        bf16x8 af[4], bfr[4];
        #pragma unroll
        for (int i = 0; i < 4; ++i) af[i] = *(const bf16x8*)(&A[wr + i * 16 + li][kk * 32 + lk]);
        #pragma unroll
        for (int j = 0; j < 4; ++j) bfr[j] = *(const bf16x8*)(&Bt[wc + j * 16 + li][kk * 32 + lk]);
        #pragma unroll
        for (int i = 0; i < 4; ++i)
            #pragma unroll
            for (int j = 0; j < 4; ++j)
                acc[i][j] = __builtin_amdgcn_mfma_f32_16x16x32_bf16(af[i], bfr[j], acc[i][j], 0, 0, 0);
    }
    int rbase = (lane >> 4) * 4;
    #pragma unroll
    for (int i = 0; i < 4; ++i) {
        #pragma unroll
        for (int j = 0; j < 4; ++j) {
            int col = wc + j * 16 + li;
            #pragma unroll
            for (int r = 0; r < 4; ++r) {
                int grow = m0 + wr + i * 16 + rbase + r;
                out[(size_t)grow * CCH + col] = acc[i][j][r] + bo[col];
            }
        }
    }
}

extern "C" void kernel_launch(void* const* d_in, const int* in_sizes, int n_in,
                              void* d_out, int out_size, void* d_ws, size_t ws_size,
                              hipStream_t stream) {
    const float* x2d  = (const float*)d_in[0];
    const float* mask = (const float*)d_in[1];
    const float* ln_g = (const float*)d_in[2];
    const float* ln_b = (const float*)d_in[3];
    const float* wq   = (const float*)d_in[4];
    const float* wk   = (const float*)d_in[5];
    const float* wv   = (const float*)d_in[6];
    const float* wb   = (const float*)d_in[7];
    const float* wg   = (const float*)d_in[8];
    const float* bg   = (const float*)d_in[9];
    const float* wo   = (const float*)d_in[10];
    const float* bo   = (const float*)d_in[11];
    float* out = (float*)d_out;

    // workspace layout (xn reused as opre after k_proj consumes it)
    char* ws = (char*)d_ws;
    unsigned short* xn   = (unsigned short*)ws;                                  // 26,214,400 B
    unsigned short* qkvg = (unsigned short*)(ws + 26214400);                     // 104,857,600 B
    float*          bterm = (float*)(ws + 26214400 + 104857600);                 // 1,638,400 B
    unsigned short* opre = xn;

    if (ws_size < (size_t)(26214400 + 104857600 + 1638400)) return;

    k_ln_bias<<<25600, 256, 0, stream>>>(x2d, ln_g, ln_b, wb, xn, bterm);
    k_proj<<<dim3(800, 4), 256, 0, stream>>>(xn, wq, wk, wv, wg, bg, qkvg);
    k_attn<<<1280, 256, 0, stream>>>(qkvg, bterm, mask, opre);
    k_out<<<800, 256, 0, stream>>>(opre, wo, bo, out);
}